// Round 18
// baseline (67.549 us; speedup 1.0000x reference)
//
#include <hip/hip_runtime.h>

typedef unsigned short u16;
typedef __attribute__((ext_vector_type(8))) __bf16 bf16x8;
typedef __attribute__((ext_vector_type(8))) unsigned short u16x8;
typedef __attribute__((ext_vector_type(4))) float f32x4;

__device__ __forceinline__ u16 f2bf(float f) {
  unsigned u = __builtin_bit_cast(unsigned, f);
  unsigned r = u + 0x7fffu + ((u >> 16) & 1u);
  return (u16)(r >> 16);
}

__device__ __forceinline__ float wave_sum(float v) {
#pragma unroll
  for (int o = 32; o; o >>= 1) v += __shfl_xor(v, o, 64);
  return v;
}

// async global(16B/lane) -> LDS (wave-uniform dest; per-lane global src)
__device__ __forceinline__ void gl2lds16(const u16* g, u16* l) {
  __builtin_amdgcn_global_load_lds(
      (const __attribute__((address_space(1))) unsigned int*)(const void*)g,
      (__attribute__((address_space(3))) unsigned int*)(void*)l, 16, 0, 0);
}

// ===== K0: plane sums (0..1023) + Mt rows (1024..1279) + xin build (1280..1535) =====
// All three branches are mutually independent (src | weights | tgt+prev) -> one launch.
// xin layout: [b][h][cg(16)][pxp(80)][slot(4)][8ch] bf16. pxp=px+1; cols 0,65..79 zero.
// slot s at pxp holds channel-octet g = s ^ ((pxp>>1)&3)  (bank swizzle).
__global__ void k0(const float* __restrict__ src, const float* __restrict__ kw,
                   const float* __restrict__ lw, const float* __restrict__ aw,
                   const float* __restrict__ gamma,
                   const float* __restrict__ tgt, const float* __restrict__ prev,
                   float* __restrict__ ssum, float* __restrict__ Mt,
                   u16* __restrict__ xin) {
  __shared__ __align__(16) unsigned char smem[33792];
  int tid = threadIdx.x;                // 512 threads
  if (blockIdx.x >= 1280) {             // ---------- xin build ----------
    u16* lt = (u16*)smem;               // 256*66 u16
    int bi = blockIdx.x - 1280;
    int b = bi >> 6, h = bi & 63;
    u16* slab = xin + (size_t)(b * 64 + h) * 40960;
    if (tid < 256) {                    // zero pads: 64B contiguous per thread
      int cg = tid >> 4, colidx = tid & 15;
      int pxp = (colidx == 0) ? 0 : (64 + colidx);
      u16x8 zz;
#pragma unroll
      for (int q = 0; q < 8; ++q) zz[q] = 0;
      u16* d = slab + cg * 2560 + pxp * 32;
      *(u16x8*)(d) = zz; *(u16x8*)(d + 8) = zz;
      *(u16x8*)(d + 16) = zz; *(u16x8*)(d + 24) = zz;
    }
#pragma unroll
    for (int it = 0; it < 8; ++it) {    // phase A: target -> lt
      int fi = it * 512 + tid;
      int c = fi >> 4, w4 = fi & 15;
      f32x4 v = *(const f32x4*)(tgt + ((size_t)(b * 256 + c) * 64 + h) * 64 + w4 * 4);
      int base = c * 66 + w4 * 4;
      lt[base] = f2bf(v[0]); lt[base + 1] = f2bf(v[1]);
      lt[base + 2] = f2bf(v[2]); lt[base + 3] = f2bf(v[3]);
    }
    __syncthreads();
    {                                   // write cg 0..7 (contiguous 1KB/wave-instr)
      int cg = tid >> 6, l = tid & 63;
      int s = l & 3;
#pragma unroll
      for (int it = 0; it < 4; ++it) {
        int pxp = 1 + it * 16 + (l >> 2);
        int g = s ^ ((pxp >> 1) & 3);
        int o = cg * 4 + g;
        int w = pxp - 1;
        u16x8 v;
#pragma unroll
        for (int k = 0; k < 8; ++k) v[k] = lt[(o * 8 + k) * 66 + w];
        *(u16x8*)(slab + cg * 2560 + pxp * 32 + s * 8) = v;
      }
    }
    __syncthreads();
#pragma unroll
    for (int it = 0; it < 4; ++it) {    // phase B: prev (2x2 upsample) -> lt
      int pi = it * 512 + tid;
      int cc = pi >> 3, wq = pi & 7;
      f32x4 v = *(const f32x4*)(prev + ((size_t)(b * 256 + cc) * 32 + (h >> 1)) * 32 + wq * 4);
      int base = cc * 66 + wq * 8;
      u16 b0 = f2bf(v[0]), b1 = f2bf(v[1]), b2 = f2bf(v[2]), b3 = f2bf(v[3]);
      lt[base] = b0; lt[base + 1] = b0; lt[base + 2] = b1; lt[base + 3] = b1;
      lt[base + 4] = b2; lt[base + 5] = b2; lt[base + 6] = b3; lt[base + 7] = b3;
    }
    __syncthreads();
    {                                   // write cg 8..15
      int cg8 = tid >> 6, l = tid & 63;
      int s = l & 3;
#pragma unroll
      for (int it = 0; it < 4; ++it) {
        int pxp = 1 + it * 16 + (l >> 2);
        int g = s ^ ((pxp >> 1) & 3);
        int o = cg8 * 4 + g;
        int w = pxp - 1;
        u16x8 v;
#pragma unroll
        for (int k = 0; k < 8; ++k) v[k] = lt[(o * 8 + k) * 66 + w];
        *(u16x8*)(slab + (8 + cg8) * 2560 + pxp * 32 + s * 8) = v;
      }
    }
    return;
  }
  if (blockIdx.x >= 1024) {             // ---------- Mt row ----------
    float* E = (float*)smem;
    int o = blockIdx.x - 1024;
    if (tid < 32) {
      float s = 0.f;
      for (int o2 = 0; o2 < 32; ++o2) s += aw[o * 288 + 256 + o2] * lw[o2 * 64 + tid];
      E[tid] = s;
    }
    __syncthreads();
    if (tid < 256) {
      float s = 0.f;
      for (int a = 0; a < 32; ++a) s += E[a] * kw[a * 256 + tid];
      Mt[o * 256 + tid] = gamma[0] * (aw[o * 288 + tid] + 4096.f * s) + (o == tid ? 1.f : 0.f);
    }
    return;
  }
  // ---------- plane sum of source_enc (512 threads) ----------
  float* red = (float*)smem;
  int plane = blockIdx.x;
  const float* p = src + (size_t)plane * 4096;
  float s = 0.f;
#pragma unroll
  for (int i = 0; i < 2; ++i) {
    f32x4 v = *(const f32x4*)(p + i * 2048 + tid * 4);
    s += v[0] + v[1] + v[2] + v[3];
  }
  s = wave_sum(s);
  if ((tid & 63) == 0) red[tid >> 6] = s;
  __syncthreads();
  if (tid == 0) {
    float t = 0.f;
#pragma unroll
    for (int i = 0; i < 8; ++i) t += red[i];
    ssum[plane] = t;
  }
}

// ===== K1: cd2 (blocks 0..35) + w3-fold Mt-tiled (36..179), 512 threads =====
// w3 u16 idx = (tap*16+cg)*4096 + kbq*1024 + oc*8 + j, channel cf = cg*32+kbq*8+j
__global__ void k1(const float* __restrict__ cw, const float* __restrict__ Mt,
                   const float* __restrict__ ssum,
                   const float* __restrict__ qw, const float* __restrict__ qb,
                   const float* __restrict__ kb, const float* __restrict__ lw,
                   const float* __restrict__ lb, const float* __restrict__ aw,
                   const float* __restrict__ ab, const float* __restrict__ gamma,
                   u16* __restrict__ w3, float* __restrict__ cd2) {
  __shared__ __align__(16) unsigned char smem[49152];
  int tid = threadIdx.x;                // 512 threads
  if (blockIdx.x < 36) {                // ---------- cd2 (9 blocks per b) ----------
    float* S = (float*)smem;
    float* part = S;                    // 512
    float* qs = S + 512;                // 32
    float* amap = S + 544;              // 32
    float* dvec = S + 576;              // 256
    int b = blockIdx.x / 9;
    int pbase = (blockIdx.x % 9) * 128;
    {                                   // qs partials: 32 o x 16 segs
      int o = tid >> 4, seg = tid & 15;
      float s = 0.f;
#pragma unroll
      for (int i = 0; i < 16; ++i) {
        int c = seg * 16 + i;
        s += qw[o * 256 + c] * ssum[b * 256 + c];
      }
      part[tid] = s;
    }
    __syncthreads();
    if (tid < 32) {
      float s = 4096.f * qb[tid];
#pragma unroll
      for (int k = 0; k < 16; ++k) s += part[tid * 16 + k];
      qs[tid] = s;
    }
    __syncthreads();
    if (tid < 32) {                     // amap[o2]
      int o2 = tid;
      float s = 0.f, kt = 0.f;
#pragma unroll
      for (int o = 0; o < 32; ++o) {
        s += lw[o2 * 64 + 32 + o] * qs[o];
        kt += lw[o2 * 64 + o] * kb[o];
      }
      amap[o2] = 4096.f * (kt + lb[o2]) + s;
    }
    __syncthreads();
    if (tid < 256) {                    // dvec[c]
      float s = ab[tid];
#pragma unroll
      for (int o2 = 0; o2 < 32; ++o2) s += aw[tid * 288 + 256 + o2] * amap[o2];
      dvec[tid] = gamma[0] * s;
    }
    __syncthreads();
    {
      int grp = tid >> 2, q = tid & 3;
      int p = pbase + grp;              // 0..1151 within this b
      int oc = p / 9, tap = p - oc * 9;
      const float* cwp = cw + (size_t)(oc * 512) * 9 + tap;
      float s0 = 0.f, s1 = 0.f, s2 = 0.f, s3 = 0.f;
#pragma unroll
      for (int i = 0; i < 16; ++i) {
        int c = q * 64 + i * 4;
        s0 += cwp[(size_t)c * 9] * dvec[c];
        s1 += cwp[(size_t)(c + 1) * 9] * dvec[c + 1];
        s2 += cwp[(size_t)(c + 2) * 9] * dvec[c + 2];
        s3 += cwp[(size_t)(c + 3) * 9] * dvec[c + 3];
      }
      float s = (s0 + s1) + (s2 + s3);
      s += __shfl_xor(s, 1, 64);
      s += __shfl_xor(s, 2, 64);
      if (q == 0) cd2[(size_t)(b * 128 + oc) * 9 + tap] = s;
    }
    return;
  }
  // ---------- w3-fold (Mt tiled via LDS) ----------
  float* cwl = (float*)smem;            // 4096 floats
  float* mtile = (float*)smem + 4096;   // 8192 floats = 32 Mt rows
  int blk = blockIdx.x - 36;            // 144 = 9*16
  int tap = blk >> 4, ocg = blk & 15;
  for (int e = tid; e < 4096; e += 512) {
    int oc = e >> 9, c = e & 511;
    cwl[e] = cw[(size_t)((ocg * 8 + oc) * 512 + c) * 9 + tap];
  }
  int wv = tid >> 6, l = tid & 63;
  int c2 = l * 4;
  f32x4 acc = {0.f, 0.f, 0.f, 0.f};
  for (int cb = 0; cb < 8; ++cb) {
    __syncthreads();                    // mtile safe to overwrite / cwl ready (cb==0)
#pragma unroll
    for (int i = 0; i < 4; ++i) {       // stage 32 rows of Mt, fully coalesced
      int e = i * 512 + tid;            // f32x4 index in [0,2048)
      ((f32x4*)mtile)[e] = *(const f32x4*)(Mt + cb * 8192 + e * 4);
    }
    __syncthreads();
#pragma unroll
    for (int cc = 0; cc < 32; ++cc) {
      float wc = cwl[wv * 512 + cb * 32 + cc];
      f32x4 m = *(const f32x4*)(mtile + cc * 256 + c2);
#pragma unroll
      for (int j = 0; j < 4; ++j) acc[j] += wc * m[j];
    }
  }
  int ocf = ocg * 8 + wv;
#pragma unroll
  for (int j2 = 0; j2 < 4; ++j2) {
    int cf = c2 + j2;
    w3[(tap * 16 + (cf >> 5)) * 4096 + ((cf >> 3) & 3) * 1024 + ocf * 8 + (cf & 7)] = f2bf(acc[j2]);
    cf = 256 + c2 + j2;
    w3[(tap * 16 + (cf >> 5)) * 4096 + ((cf >> 3) & 3) * 1024 + ocf * 8 + (cf & 7)] =
        f2bf(cwl[wv * 512 + (c2 + j2 + 256)]);
  }
}

// ===== K4: conv, counted-vmcnt pipeline, 8 WAVES + T5 setprio. =====
// block=(b,h): M=128 oc, N=64 px. (best measured config; ~85-90% of LDS-port floor)
__global__ __launch_bounds__(512) void k_conv(const u16* __restrict__ xin,
                                              const u16* __restrict__ w3,
                                              const float* __restrict__ cd2,
                                              float* __restrict__ out) {
  __shared__ u16 lds[52736];            // w3 3x12288 | xin 2x7680 | dummy 512
  const int XIN0 = 36864, DUMMY = 52224;
  int bid = blockIdx.x;                 // 256
  int lid = (bid & 7) * 32 + (bid >> 3);  // XCD-chunked
  int b = lid >> 6, h = lid & 63;
  int tid = threadIdx.x, l = tid & 63, wv = tid >> 6;   // wv 0..7
  int wr = wv & 3, wpx = wv >> 2;       // wave: M32 quarter x N32 half
  int r = l & 15, kb4 = l >> 4;

  if (h == 0 || h == 63) {
    int row = (h == 0) ? 0 : 2;
    for (int i = tid; i < 640; i += 512) {
      int bu = i / 320, off = (i % 320) * 8;
      u16x8 zz;
#pragma unroll
      for (int q = 0; q < 8; ++q) zz[q] = 0;
      *(u16x8*)(lds + XIN0 + bu * 7680 + row * 2560 + off) = zz;
    }
  }

  auto ISSUE_W3 = [&](int c2, int dy2, int buf, bool dummy) {
    u16* dst0 = lds + buf * 12288;
#pragma unroll
    for (int i = 0; i < 3; ++i) {
      int k = wv + 8 * i;               // 0..23
      int dx = k >> 3, part = k & 7;
      const u16* src = dummy ? (w3 + l * 8)
          : (w3 + (size_t)(((dy2 * 3 + dx) * 16 + c2) << 12) + part * 512 + l * 8);
      u16* dst = dummy ? (lds + DUMMY) : (dst0 + dx * 4096 + part * 512);
      gl2lds16(src, dst);
    }
  };
  auto ISSUE_XIN = [&](int c1, int buf, bool dummyAll) {
    u16* dst0 = lds + XIN0 + buf * 7680;
#pragma unroll
    for (int i = 0; i < 2; ++i) {
      int k = wv + 8 * i;               // 0..15 (k==15 is the pad chunk)
      int row = k / 5, part = k - row * 5;
      int grow = h - 1 + row;
      bool dm = dummyAll || (k == 15) || ((unsigned)grow >= 64u);
      const u16* src = dm ? (xin + l * 8)
          : (xin + ((size_t)(b * 64 + grow) * 16 + c1) * 2560 + part * 512 + l * 8);
      u16* dst = dm ? (lds + DUMMY) : (dst0 + row * 2560 + part * 512);
      gl2lds16(src, dst);
    }
  };

  f32x4 acc[2][2];
#pragma unroll
  for (int mf = 0; mf < 2; ++mf)
#pragma unroll
    for (int nf = 0; nf < 2; ++nf) acc[mf][nf] = f32x4{0.f, 0.f, 0.f, 0.f};

  ISSUE_W3(0, 0, 0, false);
  ISSUE_XIN(0, 0, false);
  ISSUE_W3(0, 1, 1, false);

  for (int c = 0; c < 16; ++c) {
#pragma unroll
    for (int dy = 0; dy < 3; ++dy) {
      if (dy == 0) asm volatile("s_waitcnt vmcnt(3) lgkmcnt(0)" ::: "memory");
      else         asm volatile("s_waitcnt vmcnt(5) lgkmcnt(0)" ::: "memory");
      __builtin_amdgcn_s_barrier();
      __builtin_amdgcn_sched_barrier(0);
      {
        int c2 = c + ((dy + 2) / 3);
        ISSUE_W3(c2, (dy + 2) % 3, (dy + 2) % 3, c2 > 15);
      }
      if (dy == 0) ISSUE_XIN(c + 1, (c + 1) & 1, c + 1 > 15);
      const u16* wbuf = lds + dy * 12288;           // s%3 == dy
      const u16* xrow = lds + XIN0 + (c & 1) * 7680 + dy * 2560;
      __builtin_amdgcn_s_setprio(1);
#pragma unroll
      for (int dx = 0; dx < 3; ++dx) {
        bf16x8 av[2];
#pragma unroll
        for (int mf = 0; mf < 2; ++mf)
          av[mf] = *(const bf16x8*)(wbuf + dx * 4096 + kb4 * 1024 + (wr * 32 + mf * 16 + r) * 8);
        bf16x8 bv[2];
#pragma unroll
        for (int nf = 0; nf < 2; ++nf) {
          int pxp = wpx * 32 + nf * 16 + r + dx;
          int slot = kb4 ^ ((pxp >> 1) & 3);
          bv[nf] = *(const bf16x8*)(xrow + pxp * 32 + slot * 8);
        }
#pragma unroll
        for (int mf = 0; mf < 2; ++mf)
#pragma unroll
          for (int nf = 0; nf < 2; ++nf)
            acc[mf][nf] = __builtin_amdgcn_mfma_f32_16x16x32_bf16(av[mf], bv[nf], acc[mf][nf], 0, 0, 0);
      }
      __builtin_amdgcn_s_setprio(0);
    }
  }

  bool dy0v = (h > 0), dy2v = (h < 63);
#pragma unroll
  for (int mf = 0; mf < 2; ++mf) {
#pragma unroll
    for (int j = 0; j < 4; ++j) {
      int oc = wr * 32 + mf * 16 + kb4 * 4 + j;
      const float* cd = cd2 + (size_t)(b * 128 + oc) * 9;
      float sAll = 0.f, sL = 0.f, sR = 0.f;
#pragma unroll
      for (int dy3 = 0; dy3 < 3; ++dy3) {
        bool v = (dy3 == 1) || (dy3 == 0 ? dy0v : dy2v);
        if (v) {
          sAll += cd[dy3 * 3] + cd[dy3 * 3 + 1] + cd[dy3 * 3 + 2];
          sL += cd[dy3 * 3];
          sR += cd[dy3 * 3 + 2];
        }
      }
#pragma unroll
      for (int nf = 0; nf < 2; ++nf) {
        int px = wpx * 32 + nf * 16 + r;
        float corr = sAll - (px == 0 ? sL : 0.f) - (px == 63 ? sR : 0.f);
        out[(size_t)(b * 128 + oc) * 4096 + h * 64 + px] = acc[mf][nf][j] + corr;
      }
    }
  }
}

// ===== K5: in-place instance norm + relu =====
__global__ void k_norm(float* __restrict__ out) {
  int plane = blockIdx.x;               // 512 = 4*128
  float* p = out + (size_t)plane * 4096;
  int t = threadIdx.x;
  f32x4 v[4];
  float s = 0.f, s2 = 0.f;
#pragma unroll
  for (int i = 0; i < 4; ++i) {
    v[i] = *(const f32x4*)(p + (i * 256 + t) * 4);
#pragma unroll
    for (int k = 0; k < 4; ++k) { s += v[i][k]; s2 += v[i][k] * v[i][k]; }
  }
  s = wave_sum(s); s2 = wave_sum(s2);
  __shared__ float rs[4], rs2[4];
  if ((t & 63) == 0) { rs[t >> 6] = s; rs2[t >> 6] = s2; }
  __syncthreads();
  float S = rs[0] + rs[1] + rs[2] + rs[3];
  float S2 = rs2[0] + rs2[1] + rs2[2] + rs2[3];
  float mean = S * (1.f / 4096.f);
  float var = S2 * (1.f / 4096.f) - mean * mean;
  float inv = rsqrtf(var + 1e-5f);
#pragma unroll
  for (int i = 0; i < 4; ++i) {
    f32x4 o;
#pragma unroll
    for (int k = 0; k < 4; ++k) {
      float y = (v[i][k] - mean) * inv;
      o[k] = y > 0.f ? y : 0.f;
    }
    *(f32x4*)(p + (i * 256 + t) * 4) = o;
  }
}

extern "C" void kernel_launch(void* const* d_in, const int* in_sizes, int n_in,
                              void* d_out, int out_size, void* d_ws, size_t ws_size,
                              hipStream_t stream) {
  const float* src    = (const float*)d_in[0];
  const float* tgt    = (const float*)d_in[1];
  const float* prev   = (const float*)d_in[2];
  const float* key_w  = (const float*)d_in[3];
  const float* key_b  = (const float*)d_in[4];
  const float* qry_w  = (const float*)d_in[5];
  const float* qry_b  = (const float*)d_in[6];
  const float* lin_w  = (const float*)d_in[7];
  const float* lin_b  = (const float*)d_in[8];
  const float* attn_w = (const float*)d_in[9];
  const float* attn_b = (const float*)d_in[10];
  const float* gamma  = (const float*)d_in[11];
  const float* conv_w = (const float*)d_in[12];
  // d_in[13] = conv_b: dropped — per-(b,oc) constant cancels under instance norm.

  char* ws = (char*)d_ws;
  size_t off = 0;
  u16*   xin  = (u16*)(ws + off);  off += 20971520;            // 256 slabs * 40960 u16
  float* ssum = (float*)(ws + off); off += 4096;               // 4*256
  float* Mt   = (float*)(ws + off); off += 262144;             // 256*256
  float* cd2  = (float*)(ws + off); off += 18432;              // 4*128*9
  u16*   w3   = (u16*)(ws + off);  off += 1179648;             // 9*16*4096 u16
  float* out  = (float*)d_out;

  k0<<<1536, 512, 0, stream>>>(src, key_w, lin_w, attn_w, gamma, tgt, prev,
                               ssum, Mt, xin);
  k1<<<180, 512, 0, stream>>>(conv_w, Mt, ssum, qry_w, qry_b, key_b, lin_w, lin_b,
                              attn_w, attn_b, gamma, w3, cd2);
  k_conv<<<256, 512, 0, stream>>>(xin, w3, cd2, out);
  k_norm<<<512, 256, 0, stream>>>(out);
}

// Round 19
// 60.736 us; speedup vs baseline: 1.1122x; 1.1122x over previous
//
#include <hip/hip_runtime.h>

typedef unsigned short u16;
typedef __attribute__((ext_vector_type(8))) __bf16 bf16x8;
typedef __attribute__((ext_vector_type(8))) unsigned short u16x8;
typedef __attribute__((ext_vector_type(4))) float f32x4;

__device__ __forceinline__ u16 f2bf(float f) {
  unsigned u = __builtin_bit_cast(unsigned, f);
  unsigned r = u + 0x7fffu + ((u >> 16) & 1u);
  return (u16)(r >> 16);
}

__device__ __forceinline__ float wave_sum(float v) {
#pragma unroll
  for (int o = 32; o; o >>= 1) v += __shfl_xor(v, o, 64);
  return v;
}

// async global(16B/lane) -> LDS (wave-uniform dest; per-lane global src)
__device__ __forceinline__ void gl2lds16(const u16* g, u16* l) {
  __builtin_amdgcn_global_load_lds(
      (const __attribute__((address_space(1))) unsigned int*)(const void*)g,
      (__attribute__((address_space(3))) unsigned int*)(void*)l, 16, 0, 0);
}

// ===== K0: plane sums (blocks 0..1023) + Mt rows (1024..1279) =====
__global__ void k0(const float* __restrict__ src, const float* __restrict__ kw,
                   const float* __restrict__ lw, const float* __restrict__ aw,
                   const float* __restrict__ gamma,
                   float* __restrict__ ssum, float* __restrict__ Mt) {
  __shared__ float red[64];
  int tid = threadIdx.x;
  if (blockIdx.x >= 1024) {             // ---- Mt row ----
    int o = blockIdx.x - 1024;
    if (tid < 32) {
      float s = 0.f;
      for (int o2 = 0; o2 < 32; ++o2) s += aw[o * 288 + 256 + o2] * lw[o2 * 64 + tid];
      red[tid] = s;
    }
    __syncthreads();
    float s = 0.f;
    for (int a = 0; a < 32; ++a) s += red[a] * kw[a * 256 + tid];
    Mt[o * 256 + tid] = gamma[0] * (aw[o * 288 + tid] + 4096.f * s) + (o == tid ? 1.f : 0.f);
    return;
  }
  // ---- plane sum of source_enc ----
  int plane = blockIdx.x;
  const float* p = src + (size_t)plane * 4096;
  float s = 0.f;
#pragma unroll
  for (int i = 0; i < 4; ++i) {
    f32x4 v = *(const f32x4*)(p + (i * 256 + tid) * 4);
    s += v[0] + v[1] + v[2] + v[3];
  }
  s = wave_sum(s);
  if ((tid & 63) == 0) red[tid >> 6] = s;
  __syncthreads();
  if (tid == 0) ssum[plane] = red[0] + red[1] + red[2] + red[3];
}

// ===== K1: cd2 (blocks 0..35) + w3-fold Mt-tiled (36..179) + xin build (180..435) =====
// xin layout: [b][h][cg(16)][pxp(80)][slot(4)][8ch] bf16. pxp=px+1; cols 0,65..79 zero.
// slot s at pxp holds channel-octet g = s ^ ((pxp>>1)&3)  (bank swizzle).
// w3 u16 idx = (tap*16+cg)*4096 + kbq*1024 + oc*8 + j, channel cf = cg*32+kbq*8+j
__global__ void k1(const float* __restrict__ tgt, const float* __restrict__ prev,
                   const float* __restrict__ cw, const float* __restrict__ Mt,
                   const float* __restrict__ ssum,
                   const float* __restrict__ qw, const float* __restrict__ qb,
                   const float* __restrict__ kb, const float* __restrict__ lw,
                   const float* __restrict__ lb, const float* __restrict__ aw,
                   const float* __restrict__ ab, const float* __restrict__ gamma,
                   u16* __restrict__ xin, u16* __restrict__ w3,
                   float* __restrict__ cd2) {
  __shared__ __align__(16) unsigned char smem[49152];   // branch-overlaid union
  int tid = threadIdx.x;                // 512 threads
  if (blockIdx.x < 36) {                // ---------- cd2 (9 blocks per b) ----------
    float* S = (float*)smem;
    float* part = S;                    // 512
    float* qs = S + 512;                // 32
    float* amap = S + 544;              // 32
    float* dvec = S + 576;              // 256
    int b = blockIdx.x / 9;
    int pbase = (blockIdx.x % 9) * 128;
    {                                   // qs partials: 32 o x 16 segs
      int o = tid >> 4, seg = tid & 15;
      float s = 0.f;
#pragma unroll
      for (int i = 0; i < 16; ++i) {
        int c = seg * 16 + i;
        s += qw[o * 256 + c] * ssum[b * 256 + c];
      }
      part[tid] = s;
    }
    __syncthreads();
    if (tid < 32) {
      float s = 4096.f * qb[tid];
#pragma unroll
      for (int k = 0; k < 16; ++k) s += part[tid * 16 + k];
      qs[tid] = s;
    }
    __syncthreads();
    if (tid < 32) {                     // amap[o2]
      int o2 = tid;
      float s = 0.f, kt = 0.f;
#pragma unroll
      for (int o = 0; o < 32; ++o) {
        s += lw[o2 * 64 + 32 + o] * qs[o];
        kt += lw[o2 * 64 + o] * kb[o];
      }
      amap[o2] = 4096.f * (kt + lb[o2]) + s;
    }
    __syncthreads();
    if (tid < 256) {                    // dvec[c]
      float s = ab[tid];
#pragma unroll
      for (int o2 = 0; o2 < 32; ++o2) s += aw[tid * 288 + 256 + o2] * amap[o2];
      dvec[tid] = gamma[0] * s;
    }
    __syncthreads();
    // pair p = pbase + (tid>>2); 4-lane group sums 64 c each, 4 indep accumulators
    {
      int grp = tid >> 2, q = tid & 3;
      int p = pbase + grp;              // 0..1151 within this b
      int oc = p / 9, tap = p - oc * 9;
      const float* cwp = cw + (size_t)(oc * 512) * 9 + tap;
      float s0 = 0.f, s1 = 0.f, s2 = 0.f, s3 = 0.f;
#pragma unroll
      for (int i = 0; i < 16; ++i) {
        int c = q * 64 + i * 4;
        s0 += cwp[(size_t)c * 9] * dvec[c];
        s1 += cwp[(size_t)(c + 1) * 9] * dvec[c + 1];
        s2 += cwp[(size_t)(c + 2) * 9] * dvec[c + 2];
        s3 += cwp[(size_t)(c + 3) * 9] * dvec[c + 3];
      }
      float s = (s0 + s1) + (s2 + s3);
      s += __shfl_xor(s, 1, 64);
      s += __shfl_xor(s, 2, 64);
      if (q == 0) cd2[(size_t)(b * 128 + oc) * 9 + tap] = s;
    }
    return;
  }
  if (blockIdx.x < 180) {               // ---------- w3-fold (Mt tiled via LDS) ----------
    float* cwl = (float*)smem;          // 4096 floats
    float* mtile = (float*)smem + 4096; // 8192 floats = 32 Mt rows
    int blk = blockIdx.x - 36;          // 144 = 9*16
    int tap = blk >> 4, ocg = blk & 15;
    for (int e = tid; e < 4096; e += 512) {
      int oc = e >> 9, c = e & 511;
      cwl[e] = cw[(size_t)((ocg * 8 + oc) * 512 + c) * 9 + tap];
    }
    int wv = tid >> 6, l = tid & 63;
    int c2 = l * 4;
    f32x4 acc = {0.f, 0.f, 0.f, 0.f};
    for (int cb = 0; cb < 8; ++cb) {
      __syncthreads();                  // mtile safe to overwrite / cwl ready (cb==0)
#pragma unroll
      for (int i = 0; i < 4; ++i) {     // stage 32 rows of Mt, fully coalesced
        int e = i * 512 + tid;          // f32x4 index in [0,2048)
        ((f32x4*)mtile)[e] = *(const f32x4*)(Mt + cb * 8192 + e * 4);
      }
      __syncthreads();
#pragma unroll
      for (int cc = 0; cc < 32; ++cc) {
        float wc = cwl[wv * 512 + cb * 32 + cc];
        f32x4 m = *(const f32x4*)(mtile + cc * 256 + c2);
#pragma unroll
        for (int j = 0; j < 4; ++j) acc[j] += wc * m[j];
      }
    }
    int ocf = ocg * 8 + wv;
#pragma unroll
    for (int j2 = 0; j2 < 4; ++j2) {
      int cf = c2 + j2;
      w3[(tap * 16 + (cf >> 5)) * 4096 + ((cf >> 3) & 3) * 1024 + ocf * 8 + (cf & 7)] = f2bf(acc[j2]);
      cf = 256 + c2 + j2;
      w3[(tap * 16 + (cf >> 5)) * 4096 + ((cf >> 3) & 3) * 1024 + ocf * 8 + (cf & 7)] =
          f2bf(cwl[wv * 512 + (c2 + j2 + 256)]);
    }
    return;
  }
  // ---------- xin build: coalesced loads -> LDS -> contiguous swizzled stores ----------
  u16* lt = (u16*)smem;                 // 256*66 u16 = 33792 B
  int bi = blockIdx.x - 180;
  int b = bi >> 6, h = bi & 63;
  u16* slab = xin + (size_t)(b * 64 + h) * 40960;
  // zero pads: 256 threads x 64B contiguous each (16 cg x 16 pad-cols)
  if (tid < 256) {
    int cg = tid >> 4, colidx = tid & 15;
    int pxp = (colidx == 0) ? 0 : (64 + colidx);
    u16x8 zz;
#pragma unroll
    for (int q = 0; q < 8; ++q) zz[q] = 0;
    u16* d = slab + cg * 2560 + pxp * 32;
    *(u16x8*)(d) = zz; *(u16x8*)(d + 8) = zz;
    *(u16x8*)(d + 16) = zz; *(u16x8*)(d + 24) = zz;
  }
  // phase A: target -> lt (coalesced f32x4)
#pragma unroll
  for (int it = 0; it < 8; ++it) {
    int fi = it * 512 + tid;
    int c = fi >> 4, w4 = fi & 15;
    f32x4 v = *(const f32x4*)(tgt + ((size_t)(b * 256 + c) * 64 + h) * 64 + w4 * 4);
    int base = c * 66 + w4 * 4;
    lt[base] = f2bf(v[0]); lt[base + 1] = f2bf(v[1]);
    lt[base + 2] = f2bf(v[2]); lt[base + 3] = f2bf(v[3]);
  }
  __syncthreads();
  // write cg 0..7: lane-fast slot -> wave writes 1KB fully contiguous per instr
  {
    int cg = tid >> 6, l = tid & 63;
    int s = l & 3;
#pragma unroll
    for (int it = 0; it < 4; ++it) {
      int pxp = 1 + it * 16 + (l >> 2);
      int g = s ^ ((pxp >> 1) & 3);
      int o = cg * 4 + g;
      int w = pxp - 1;
      u16x8 v;
#pragma unroll
      for (int k = 0; k < 8; ++k) v[k] = lt[(o * 8 + k) * 66 + w];
      *(u16x8*)(slab + cg * 2560 + pxp * 32 + s * 8) = v;
    }
  }
  __syncthreads();
  // phase B: prev (2x2 upsample) -> lt
#pragma unroll
  for (int it = 0; it < 4; ++it) {
    int pi = it * 512 + tid;
    int cc = pi >> 3, wq = pi & 7;
    f32x4 v = *(const f32x4*)(prev + ((size_t)(b * 256 + cc) * 32 + (h >> 1)) * 32 + wq * 4);
    int base = cc * 66 + wq * 8;
    u16 b0 = f2bf(v[0]), b1 = f2bf(v[1]), b2 = f2bf(v[2]), b3 = f2bf(v[3]);
    lt[base] = b0; lt[base + 1] = b0; lt[base + 2] = b1; lt[base + 3] = b1;
    lt[base + 4] = b2; lt[base + 5] = b2; lt[base + 6] = b3; lt[base + 7] = b3;
  }
  __syncthreads();
  // write cg 8..15 (same contiguous mapping)
  {
    int cg8 = tid >> 6, l = tid & 63;
    int s = l & 3;
#pragma unroll
    for (int it = 0; it < 4; ++it) {
      int pxp = 1 + it * 16 + (l >> 2);
      int g = s ^ ((pxp >> 1) & 3);
      int o = cg8 * 4 + g;
      int w = pxp - 1;
      u16x8 v;
#pragma unroll
      for (int k = 0; k < 8; ++k) v[k] = lt[(o * 8 + k) * 66 + w];
      *(u16x8*)(slab + (8 + cg8) * 2560 + pxp * 32 + s * 8) = v;
    }
  }
}

// ===== K4: conv, counted-vmcnt pipeline, 8 WAVES + T5 setprio. =====
// block=(b,h): M=128 oc, N=64 px. (best measured config; ~85-90% of LDS-port floor)
__global__ __launch_bounds__(512) void k_conv(const u16* __restrict__ xin,
                                              const u16* __restrict__ w3,
                                              const float* __restrict__ cd2,
                                              float* __restrict__ out) {
  __shared__ u16 lds[52736];            // w3 3x12288 | xin 2x7680 | dummy 512
  const int XIN0 = 36864, DUMMY = 52224;
  int bid = blockIdx.x;                 // 256
  int lid = (bid & 7) * 32 + (bid >> 3);  // XCD-chunked
  int b = lid >> 6, h = lid & 63;
  int tid = threadIdx.x, l = tid & 63, wv = tid >> 6;   // wv 0..7
  int wr = wv & 3, wpx = wv >> 2;       // wave: M32 quarter x N32 half
  int r = l & 15, kb4 = l >> 4;

  if (h == 0 || h == 63) {
    int row = (h == 0) ? 0 : 2;
    for (int i = tid; i < 640; i += 512) {
      int bu = i / 320, off = (i % 320) * 8;
      u16x8 zz;
#pragma unroll
      for (int q = 0; q < 8; ++q) zz[q] = 0;
      *(u16x8*)(lds + XIN0 + bu * 7680 + row * 2560 + off) = zz;
    }
  }

  auto ISSUE_W3 = [&](int c2, int dy2, int buf, bool dummy) {
    u16* dst0 = lds + buf * 12288;
#pragma unroll
    for (int i = 0; i < 3; ++i) {
      int k = wv + 8 * i;               // 0..23
      int dx = k >> 3, part = k & 7;
      const u16* src = dummy ? (w3 + l * 8)
          : (w3 + (size_t)(((dy2 * 3 + dx) * 16 + c2) << 12) + part * 512 + l * 8);
      u16* dst = dummy ? (lds + DUMMY) : (dst0 + dx * 4096 + part * 512);
      gl2lds16(src, dst);
    }
  };
  auto ISSUE_XIN = [&](int c1, int buf, bool dummyAll) {
    u16* dst0 = lds + XIN0 + buf * 7680;
#pragma unroll
    for (int i = 0; i < 2; ++i) {
      int k = wv + 8 * i;               // 0..15 (k==15 is the pad chunk)
      int row = k / 5, part = k - row * 5;
      int grow = h - 1 + row;
      bool dm = dummyAll || (k == 15) || ((unsigned)grow >= 64u);
      const u16* src = dm ? (xin + l * 8)
          : (xin + ((size_t)(b * 64 + grow) * 16 + c1) * 2560 + part * 512 + l * 8);
      u16* dst = dm ? (lds + DUMMY) : (dst0 + row * 2560 + part * 512);
      gl2lds16(src, dst);
    }
  };

  f32x4 acc[2][2];
#pragma unroll
  for (int mf = 0; mf < 2; ++mf)
#pragma unroll
    for (int nf = 0; nf < 2; ++nf) acc[mf][nf] = f32x4{0.f, 0.f, 0.f, 0.f};

  ISSUE_W3(0, 0, 0, false);
  ISSUE_XIN(0, 0, false);
  ISSUE_W3(0, 1, 1, false);

  for (int c = 0; c < 16; ++c) {
#pragma unroll
    for (int dy = 0; dy < 3; ++dy) {
      if (dy == 0) asm volatile("s_waitcnt vmcnt(3) lgkmcnt(0)" ::: "memory");
      else         asm volatile("s_waitcnt vmcnt(5) lgkmcnt(0)" ::: "memory");
      __builtin_amdgcn_s_barrier();
      __builtin_amdgcn_sched_barrier(0);
      {
        int c2 = c + ((dy + 2) / 3);
        ISSUE_W3(c2, (dy + 2) % 3, (dy + 2) % 3, c2 > 15);
      }
      if (dy == 0) ISSUE_XIN(c + 1, (c + 1) & 1, c + 1 > 15);
      const u16* wbuf = lds + dy * 12288;           // s%3 == dy
      const u16* xrow = lds + XIN0 + (c & 1) * 7680 + dy * 2560;
      __builtin_amdgcn_s_setprio(1);
#pragma unroll
      for (int dx = 0; dx < 3; ++dx) {
        bf16x8 av[2];
#pragma unroll
        for (int mf = 0; mf < 2; ++mf)
          av[mf] = *(const bf16x8*)(wbuf + dx * 4096 + kb4 * 1024 + (wr * 32 + mf * 16 + r) * 8);
        bf16x8 bv[2];
#pragma unroll
        for (int nf = 0; nf < 2; ++nf) {
          int pxp = wpx * 32 + nf * 16 + r + dx;
          int slot = kb4 ^ ((pxp >> 1) & 3);
          bv[nf] = *(const bf16x8*)(xrow + pxp * 32 + slot * 8);
        }
#pragma unroll
        for (int mf = 0; mf < 2; ++mf)
#pragma unroll
          for (int nf = 0; nf < 2; ++nf)
            acc[mf][nf] = __builtin_amdgcn_mfma_f32_16x16x32_bf16(av[mf], bv[nf], acc[mf][nf], 0, 0, 0);
      }
      __builtin_amdgcn_s_setprio(0);
    }
  }

  bool dy0v = (h > 0), dy2v = (h < 63);
#pragma unroll
  for (int mf = 0; mf < 2; ++mf) {
#pragma unroll
    for (int j = 0; j < 4; ++j) {
      int oc = wr * 32 + mf * 16 + kb4 * 4 + j;
      const float* cd = cd2 + (size_t)(b * 128 + oc) * 9;
      float sAll = 0.f, sL = 0.f, sR = 0.f;
#pragma unroll
      for (int dy3 = 0; dy3 < 3; ++dy3) {
        bool v = (dy3 == 1) || (dy3 == 0 ? dy0v : dy2v);
        if (v) {
          sAll += cd[dy3 * 3] + cd[dy3 * 3 + 1] + cd[dy3 * 3 + 2];
          sL += cd[dy3 * 3];
          sR += cd[dy3 * 3 + 2];
        }
      }
#pragma unroll
      for (int nf = 0; nf < 2; ++nf) {
        int px = wpx * 32 + nf * 16 + r;
        float corr = sAll - (px == 0 ? sL : 0.f) - (px == 63 ? sR : 0.f);
        out[(size_t)(b * 128 + oc) * 4096 + h * 64 + px] = acc[mf][nf][j] + corr;
      }
    }
  }
}

// ===== K5: in-place instance norm + relu =====
__global__ void k_norm(float* __restrict__ out) {
  int plane = blockIdx.x;               // 512 = 4*128
  float* p = out + (size_t)plane * 4096;
  int t = threadIdx.x;
  f32x4 v[4];
  float s = 0.f, s2 = 0.f;
#pragma unroll
  for (int i = 0; i < 4; ++i) {
    v[i] = *(const f32x4*)(p + (i * 256 + t) * 4);
#pragma unroll
    for (int k = 0; k < 4; ++k) { s += v[i][k]; s2 += v[i][k] * v[i][k]; }
  }
  s = wave_sum(s); s2 = wave_sum(s2);
  __shared__ float rs[4], rs2[4];
  if ((t & 63) == 0) { rs[t >> 6] = s; rs2[t >> 6] = s2; }
  __syncthreads();
  float S = rs[0] + rs[1] + rs[2] + rs[3];
  float S2 = rs2[0] + rs2[1] + rs2[2] + rs2[3];
  float mean = S * (1.f / 4096.f);
  float var = S2 * (1.f / 4096.f) - mean * mean;
  float inv = rsqrtf(var + 1e-5f);
#pragma unroll
  for (int i = 0; i < 4; ++i) {
    f32x4 o;
#pragma unroll
    for (int k = 0; k < 4; ++k) {
      float y = (v[i][k] - mean) * inv;
      o[k] = y > 0.f ? y : 0.f;
    }
    *(f32x4*)(p + (i * 256 + t) * 4) = o;
  }
}

extern "C" void kernel_launch(void* const* d_in, const int* in_sizes, int n_in,
                              void* d_out, int out_size, void* d_ws, size_t ws_size,
                              hipStream_t stream) {
  const float* src    = (const float*)d_in[0];
  const float* tgt    = (const float*)d_in[1];
  const float* prev   = (const float*)d_in[2];
  const float* key_w  = (const float*)d_in[3];
  const float* key_b  = (const float*)d_in[4];
  const float* qry_w  = (const float*)d_in[5];
  const float* qry_b  = (const float*)d_in[6];
  const float* lin_w  = (const float*)d_in[7];
  const float* lin_b  = (const float*)d_in[8];
  const float* attn_w = (const float*)d_in[9];
  const float* attn_b = (const float*)d_in[10];
  const float* gamma  = (const float*)d_in[11];
  const float* conv_w = (const float*)d_in[12];
  // d_in[13] = conv_b: dropped — per-(b,oc) constant cancels under instance norm.

  char* ws = (char*)d_ws;
  size_t off = 0;
  u16*   xin  = (u16*)(ws + off);  off += 20971520;            // 256 slabs * 40960 u16
  float* ssum = (float*)(ws + off); off += 4096;               // 4*256
  float* Mt   = (float*)(ws + off); off += 262144;             // 256*256
  float* cd2  = (float*)(ws + off); off += 18432;              // 4*128*9
  u16*   w3   = (u16*)(ws + off);  off += 1179648;             // 9*16*4096 u16
  float* out  = (float*)d_out;

  k0<<<1280, 256, 0, stream>>>(src, key_w, lin_w, attn_w, gamma, ssum, Mt);
  k1<<<436, 512, 0, stream>>>(tgt, prev, conv_w, Mt, ssum, qry_w, qry_b, key_b,
                              lin_w, lin_b, attn_w, attn_b, gamma, xin, w3, cd2);
  k_conv<<<256, 512, 0, stream>>>(xin, w3, cd2, out);
  k_norm<<<512, 256, 0, stream>>>(out);
}